// Round 18
// baseline (1132.540 us; speedup 1.0000x reference)
//
#include <hip/hip_runtime.h>
#include <hip/hip_bf16.h>
#include <math.h>

typedef __attribute__((ext_vector_type(4))) float f32x4;
typedef __attribute__((ext_vector_type(8))) short bf16x8;

__device__ __forceinline__ unsigned short f2bf(float f) {
  unsigned int x = __builtin_bit_cast(unsigned int, f);
  x += 0x7fffu + ((x >> 16) & 1u);
  return (unsigned short)(x >> 16);
}
__device__ __forceinline__ float bf2f(unsigned short u) {
  unsigned int x = ((unsigned int)u) << 16;
  return __builtin_bit_cast(float, x);
}

__device__ __forceinline__ void gload_lds16(const void* g, void* l) {
  __builtin_amdgcn_global_load_lds(
      (const __attribute__((address_space(1))) unsigned int*)g,
      (__attribute__((address_space(3))) unsigned int*)l, 16, 0, 0);
}

// ---------------- fused f32 -> bf16 weight casts ----------------
__global__ void cvt_all(const float* __restrict__ s0, int n0, const float* __restrict__ s1, int n1,
                        const float* __restrict__ s2, int n2, const float* __restrict__ s3, int n3,
                        unsigned short* __restrict__ d) {
  int i = blockIdx.x * 256 + threadIdx.x;
  if (i >= n0 + n1 + n2 + n3) return;
  const float* s;
  int off;
  if (i < n0) { s = s0; off = 0; }
  else if (i < n0 + n1) { s = s1; off = n0; }
  else if (i < n0 + n1 + n2) { s = s2; off = n0 + n1; }
  else { s = s3; off = n0 + n1 + n2; }
  d[i] = f2bf(s[i - off]);
}

// ---------------- bmask precompute: rel-pos bias + shift mask, fused bf16 ----------------
// bm[wm][h][m][n] = rel[ridx(m,n)*12+h] + mask[wm][m][n]. Removes 64 scattered
// f32 gathers per lane from attn (R18 diagnosis: attn is scattered-load bound).
__global__ void bmask_build(const float* __restrict__ rel, const float* __restrict__ mask,
                            unsigned short* __restrict__ bm) {
  int i = blockIdx.x * 256 + threadIdx.x;  // 256*12*4096 total
  int n = i & 63, m = (i >> 6) & 63;
  int h = (i >> 12) % 12;
  int wm = i / 49152;
  int ridx = ((m >> 3) - (n >> 3) + 7) * 15 + (m & 7) - (n & 7) + 7;
  bm[i] = f2bf(rel[ridx * 12 + h] + mask[wm * 4096 + m * 64 + n]);
}

// ---------------- LayerNorm, f32 input (REMAP: window gather + xb emit) ----------------
template <int REMAP>
__global__ __launch_bounds__(256)
void ln_kernel(const float* __restrict__ x, const float* __restrict__ g,
               const float* __restrict__ b, unsigned short* __restrict__ dst_o,
               unsigned short* __restrict__ xb) {
  int r = blockIdx.x * 4 + (threadIdx.x >> 6);
  int lane = threadIdx.x & 63;
  size_t src;
  if (REMAP) {
    int w = r >> 6, t = r & 63;
    int bb = w >> 8, wi = (w >> 4) & 15, wj = w & 15;
    int i = t >> 3, j = t & 7;
    int p = (wi * 8 + i + 4) & 127, q = (wj * 8 + j + 4) & 127;
    src = ((size_t)bb * 16384 + p * 128 + q) * 384;
  } else {
    src = (size_t)r * 384;
  }
  float v[6];
  float s = 0.f, s2 = 0.f;
#pragma unroll
  for (int m = 0; m < 6; ++m) {
    v[m] = x[src + lane + 64 * m];
    s += v[m];
    s2 += v[m] * v[m];
  }
  if (REMAP) {
#pragma unroll
    for (int m = 0; m < 6; ++m) xb[src + lane + 64 * m] = f2bf(v[m]);
  }
#pragma unroll
  for (int o2 = 1; o2 < 64; o2 <<= 1) {
    s += __shfl_xor(s, o2);
    s2 += __shfl_xor(s2, o2);
  }
  float mu = s * (1.f / 384.f);
  float var = s2 * (1.f / 384.f) - mu * mu;
  float ri = rsqrtf(var + 1e-5f);
  size_t dst = (size_t)r * 384;
#pragma unroll
  for (int m = 0; m < 6; ++m) {
    int c = lane + 64 * m;
    dst_o[dst + c] = f2bf((v[m] - mu) * ri * g[c] + b[c]);
  }
}

// ---------------- GEMM: C(M,N) = A(M,K) * B(N,K)^T (R15 protocol, passed) ----------------
// BM=256, BN=128, BK=32, 512 thr / 8 waves, wave 64x64, acc[4][4]. Tri-buffer,
// counted vmcnt(3) (T4), stage(t+2) post-barrier, R7-style fencing.
// EPI 0: bf16(acc+bias) | 1: bf16(gelu) | 3: f32+bf16resid | 4: qkv (Q cols pre-scaled)
template <int EPI, int K, int NT>
__global__ __launch_bounds__(512, 4)
void gemmT(const unsigned short* __restrict__ A, const unsigned short* __restrict__ Bw,
           const float* __restrict__ bias, int M, int N,
           unsigned short* __restrict__ Obf, const unsigned short* __restrict__ resid,
           float* __restrict__ Of) {
  __shared__ unsigned short lds[3 * 12288];
  const int tid = threadIdx.x;
  const int lane = tid & 63;
  const int wid = tid >> 6;
  const int wm = wid >> 1, wn = wid & 1;
  const int li = lane & 15, lg = lane >> 4;

  const int nwg = gridDim.x;
  const int orig = blockIdx.x;
  const int q = nwg >> 3, r = nwg & 7;
  const int xcd = orig & 7, loc = orig >> 3;
  const int wg = (xcd < r ? xcd * (q + 1) : r * (q + 1) + (xcd - r) * q) + loc;
  const int m0 = (wg / NT) * 256;
  const int n0 = (wg % NT) * 128;

  const int srow = tid >> 2;
  const int scol = ((tid & 3) ^ ((srow >> 1) & 3)) * 8;
  const unsigned short* gA0 = A + (size_t)(m0 + srow) * K + scol;
  const unsigned short* gA1 = A + (size_t)(m0 + 128 + srow) * K + scol;
  const unsigned short* gB0 = Bw + (size_t)(n0 + srow) * K + scol;

  constexpr int nk = K >> 5;
  const int gsw = (lg ^ ((li >> 1) & 3)) * 8;
  f32x4 acc[4][4] = {};

  gload_lds16(gA0, lds + wid * 512);
  gload_lds16(gA1, lds + 4096 + wid * 512);
  gload_lds16(gB0, lds + 8192 + wid * 512);
  gload_lds16(gA0 + 32, lds + 12288 + wid * 512);
  gload_lds16(gA1 + 32, lds + 12288 + 4096 + wid * 512);
  gload_lds16(gB0 + 32, lds + 12288 + 8192 + wid * 512);

#pragma unroll
  for (int t = 0; t < nk; ++t) {
    if (t < nk - 1) {
      asm volatile("s_waitcnt vmcnt(3)" ::: "memory");
    } else {
      asm volatile("s_waitcnt vmcnt(0)" ::: "memory");
    }
    __builtin_amdgcn_s_barrier();
    __builtin_amdgcn_sched_barrier(0);
    unsigned short* const cur = lds + (t % 3) * 12288;
    if (t + 2 < nk) {
      unsigned short* const nxt = lds + ((t + 2) % 3) * 12288;
      gload_lds16(gA0 + (t + 2) * 32, nxt + wid * 512);
      gload_lds16(gA1 + (t + 2) * 32, nxt + 4096 + wid * 512);
      gload_lds16(gB0 + (t + 2) * 32, nxt + 8192 + wid * 512);
    }
    bf16x8 a[4], b[4];
#pragma unroll
    for (int f = 0; f < 4; ++f) {
      a[f] = *(const bf16x8*)&cur[(wm * 64 + f * 16 + li) * 32 + gsw];
      b[f] = *(const bf16x8*)&cur[8192 + (wn * 64 + f * 16 + li) * 32 + gsw];
    }
    __builtin_amdgcn_s_setprio(1);
#pragma unroll
    for (int mf = 0; mf < 4; ++mf)
#pragma unroll
      for (int nf = 0; nf < 4; ++nf)
        acc[mf][nf] = __builtin_amdgcn_mfma_f32_16x16x32_bf16(a[mf], b[nf], acc[mf][nf], 0, 0, 0);
    __builtin_amdgcn_s_setprio(0);
  }

#pragma unroll
  for (int mf = 0; mf < 4; ++mf) {
#pragma unroll
    for (int r2 = 0; r2 < 4; ++r2) {
      int mrow = m0 + wm * 64 + mf * 16 + lg * 4 + r2;
#pragma unroll
      for (int nf = 0; nf < 4; ++nf) {
        int col = n0 + wn * 64 + nf * 16 + li;
        float v = acc[mf][nf][r2] + bias[col];
        if (EPI == 0) {
          Obf[(size_t)mrow * N + col] = f2bf(v);
        } else if (EPI == 4) {
          // qkv: fold softmax scale into Q (cols < 384)
          float sc = (col < 384) ? 0.17677669529663688f : 1.f;
          Obf[(size_t)mrow * N + col] = f2bf(v * sc);
        } else if (EPI == 1) {
          float y = 1.5957691f * (v + 0.044715f * v * v * v);
          float gl = v * __builtin_amdgcn_rcpf(1.f + __expf(-y));
          Obf[(size_t)mrow * N + col] = f2bf(gl);
        } else {
          Of[(size_t)mrow * N + col] = v + bf2f(resid[(size_t)mrow * N + col]);
        }
      }
    }
  }
}

// ---------------- proj + window-reverse + residual + LN2, fused (R16, passed) ----------------
__global__ __launch_bounds__(512, 1)
void projln(const unsigned short* __restrict__ A, const unsigned short* __restrict__ Bw,
            const float* __restrict__ bias, const unsigned short* __restrict__ xb,
            const float* __restrict__ g2, const float* __restrict__ b2,
            unsigned short* __restrict__ x1b, unsigned short* __restrict__ ln2o) {
  constexpr int K = 384;
  __shared__ unsigned short lds[3 * 16384];
  __shared__ float rsum[128], rsum2[128];
  const int tid = threadIdx.x;
  const int lane = tid & 63;
  const int wid = tid >> 6;
  const int wm = wid >> 2, wn = wid & 3;
  const int li = lane & 15, lg = lane >> 4;

  const int nwg = gridDim.x;
  const int orig = blockIdx.x;
  const int q = nwg >> 3, r = nwg & 7;
  const int xcd = orig & 7, loc = orig >> 3;
  const int wg = (xcd < r ? xcd * (q + 1) : r * (q + 1) + (xcd - r) * q) + loc;
  const int m0 = wg * 128;

  if (tid < 128) { rsum[tid] = 0.f; rsum2[tid] = 0.f; }
  __syncthreads();

  const int srow = tid >> 2;
  const int scol = ((tid & 3) ^ ((srow >> 1) & 3)) * 8;
  const unsigned short* gA  = A + (size_t)(m0 + srow) * K + scol;
  const unsigned short* gB0 = Bw + (size_t)srow * K + scol;
  const unsigned short* gB1 = Bw + (size_t)(128 + srow) * K + scol;
  const unsigned short* gB2 = Bw + (size_t)(256 + srow) * K + scol;

  constexpr int nk = 12;
  const int gsw = (lg ^ ((li >> 1) & 3)) * 8;
  f32x4 acc[4][6] = {};

#pragma unroll
  for (int t0 = 0; t0 < 2; ++t0) {
    unsigned short* dst = lds + t0 * 16384;
    gload_lds16(gA + t0 * 32, dst + wid * 512);
    gload_lds16(gB0 + t0 * 32, dst + 4096 + wid * 512);
    gload_lds16(gB1 + t0 * 32, dst + 8192 + wid * 512);
    gload_lds16(gB2 + t0 * 32, dst + 12288 + wid * 512);
  }

#pragma unroll
  for (int t = 0; t < nk; ++t) {
    if (t < nk - 1) {
      asm volatile("s_waitcnt vmcnt(4)" ::: "memory");
    } else {
      asm volatile("s_waitcnt vmcnt(0)" ::: "memory");
    }
    __builtin_amdgcn_s_barrier();
    __builtin_amdgcn_sched_barrier(0);
    unsigned short* const cur = lds + (t % 3) * 16384;
    if (t + 2 < nk) {
      unsigned short* const nxt = lds + ((t + 2) % 3) * 16384;
      gload_lds16(gA + (t + 2) * 32, nxt + wid * 512);
      gload_lds16(gB0 + (t + 2) * 32, nxt + 4096 + wid * 512);
      gload_lds16(gB1 + (t + 2) * 32, nxt + 8192 + wid * 512);
      gload_lds16(gB2 + (t + 2) * 32, nxt + 12288 + wid * 512);
    }
    bf16x8 a[4], b[6];
#pragma unroll
    for (int f = 0; f < 4; ++f)
      a[f] = *(const bf16x8*)&cur[(wm * 64 + f * 16 + li) * 32 + gsw];
#pragma unroll
    for (int f = 0; f < 6; ++f)
      b[f] = *(const bf16x8*)&cur[4096 + (wn * 96 + f * 16 + li) * 32 + gsw];
    __builtin_amdgcn_s_setprio(1);
#pragma unroll
    for (int mf = 0; mf < 4; ++mf)
#pragma unroll
      for (int nf = 0; nf < 6; ++nf)
        acc[mf][nf] = __builtin_amdgcn_mfma_f32_16x16x32_bf16(a[mf], b[nf], acc[mf][nf], 0, 0, 0);
    __builtin_amdgcn_s_setprio(0);
  }

#pragma unroll
  for (int mf = 0; mf < 4; ++mf) {
#pragma unroll
    for (int r2 = 0; r2 < 4; ++r2) {
      int lrow = wm * 64 + mf * 16 + lg * 4 + r2;
      int mrow = m0 + lrow;
      int w = mrow >> 6, t = mrow & 63;
      int bb2 = w >> 8, wi = (w >> 4) & 15, wj = w & 15;
      int i = t >> 3, j = t & 7;
      int p = (wi * 8 + i + 4) & 127, qq = (wj * 8 + j + 4) & 127;
      size_t orow = (size_t)bb2 * 16384 + p * 128 + qq;
      float s = 0.f, s2 = 0.f;
#pragma unroll
      for (int nf = 0; nf < 6; ++nf) {
        int col = wn * 96 + nf * 16 + li;
        float v = acc[mf][nf][r2] + bias[col] + bf2f(xb[orow * 384 + col]);
        acc[mf][nf][r2] = v;
        x1b[orow * 384 + col] = f2bf(v);
        s += v;
        s2 += v * v;
      }
#pragma unroll
      for (int o2 = 1; o2 < 16; o2 <<= 1) {
        s += __shfl_xor(s, o2);
        s2 += __shfl_xor(s2, o2);
      }
      if (li == 0) {
        atomicAdd(&rsum[lrow], s);
        atomicAdd(&rsum2[lrow], s2);
      }
    }
  }
  __syncthreads();

#pragma unroll
  for (int mf = 0; mf < 4; ++mf) {
#pragma unroll
    for (int r2 = 0; r2 < 4; ++r2) {
      int lrow = wm * 64 + mf * 16 + lg * 4 + r2;
      int mrow = m0 + lrow;
      int w = mrow >> 6, t = mrow & 63;
      int bb2 = w >> 8, wi = (w >> 4) & 15, wj = w & 15;
      int i = t >> 3, j = t & 7;
      int p = (wi * 8 + i + 4) & 127, qq = (wj * 8 + j + 4) & 127;
      size_t orow = (size_t)bb2 * 16384 + p * 128 + qq;
      float mu = rsum[lrow] * (1.f / 384.f);
      float var = rsum2[lrow] * (1.f / 384.f) - mu * mu;
      float ri = rsqrtf(var + 1e-5f);
#pragma unroll
      for (int nf = 0; nf < 6; ++nf) {
        int col = wn * 96 + nf * 16 + li;
        float v = acc[mf][nf][r2];
        ln2o[orow * 384 + col] = f2bf((v - mu) * ri * g2[col] + b2[col]);
      }
    }
  }
}

// ---------------- windowed attention (bmask-fused, Q pre-scaled) ----------------
__global__ __launch_bounds__(256, 2)
void attn_kernel(const unsigned short* __restrict__ qkv, const unsigned short* __restrict__ bmask,
                 unsigned short* __restrict__ out) {
  __shared__ unsigned short v_lds[4][64 * 40];
  __shared__ unsigned short p_lds[4][64 * 72];
  const int w = blockIdx.x;
  const int hi = blockIdx.y;
  const int tid = threadIdx.x;
  const int wid = tid >> 6, lane = tid & 63;
  const int li = lane & 15, lg = lane >> 4;
  const size_t base = (size_t)w * 64;

  int h = wid * 3 + hi;
  const unsigned short* bm = bmask + (((size_t)(w & 255) * 12 + h) << 12);
  bf16x8 aq[4], bk[4];
#pragma unroll
  for (int f = 0; f < 4; ++f) {
    size_t off = (base + f * 16 + li) * 1152 + h * 32 + lg * 8;
    aq[f] = *(const bf16x8*)&qkv[off];
    bk[f] = *(const bf16x8*)&qkv[off + 384];
  }
  f32x4 s[4][4] = {};
#pragma unroll
  for (int mf = 0; mf < 4; ++mf)
#pragma unroll
    for (int nf = 0; nf < 4; ++nf)
      s[mf][nf] = __builtin_amdgcn_mfma_f32_16x16x32_bf16(aq[mf], bk[nf], s[mf][nf], 0, 0, 0);

  {
    const unsigned short* vp = &qkv[(base + lane) * 1152 + 768 + h * 32];
    unsigned short* dp = &v_lds[wid][lane * 40];
#pragma unroll
    for (int c = 0; c < 4; ++c) *(bf16x8*)&dp[c * 8] = *(const bf16x8*)&vp[c * 8];
  }

#pragma unroll
  for (int mf = 0; mf < 4; ++mf) {
#pragma unroll
    for (int r = 0; r < 4; ++r) {
      int m = mf * 16 + lg * 4 + r;
      float mx = -1e30f;
#pragma unroll
      for (int nf = 0; nf < 4; ++nf) {
        int n = nf * 16 + li;
        float val = s[mf][nf][r] + bf2f(bm[m * 64 + n]);  // Q pre-scaled; bias+mask fused
        s[mf][nf][r] = val;
        mx = fmaxf(mx, val);
      }
#pragma unroll
      for (int o2 = 1; o2 < 16; o2 <<= 1) mx = fmaxf(mx, __shfl_xor(mx, o2));
      float sum = 0.f;
#pragma unroll
      for (int nf = 0; nf < 4; ++nf) {
        float e = __expf(s[mf][nf][r] - mx);
        s[mf][nf][r] = e;
        sum += e;
      }
#pragma unroll
      for (int o2 = 1; o2 < 16; o2 <<= 1) sum += __shfl_xor(sum, o2);
      float inv = __builtin_amdgcn_rcpf(sum);
#pragma unroll
      for (int nf = 0; nf < 4; ++nf) s[mf][nf][r] *= inv;
    }
  }

#pragma unroll
  for (int mf = 0; mf < 4; ++mf)
#pragma unroll
    for (int nf = 0; nf < 4; ++nf)
#pragma unroll
      for (int r = 0; r < 4; ++r) {
        int m = mf * 16 + lg * 4 + r, n = nf * 16 + li;
        p_lds[wid][m * 72 + n] = f2bf(s[mf][nf][r]);
      }

  f32x4 o[4][2] = {};
#pragma unroll
  for (int kf = 0; kf < 2; ++kf) {
    bf16x8 bv[2];
#pragma unroll
    for (int df = 0; df < 2; ++df) {
      bf16x8 t;
#pragma unroll
      for (int e = 0; e < 8; ++e)
        t[e] = (short)v_lds[wid][(kf * 32 + lg * 8 + e) * 40 + df * 16 + li];
      bv[df] = t;
    }
#pragma unroll
    for (int mf = 0; mf < 4; ++mf) {
      bf16x8 pa = *(const bf16x8*)&p_lds[wid][(mf * 16 + li) * 72 + kf * 32 + lg * 8];
#pragma unroll
      for (int df = 0; df < 2; ++df)
        o[mf][df] = __builtin_amdgcn_mfma_f32_16x16x32_bf16(pa, bv[df], o[mf][df], 0, 0, 0);
    }
  }

#pragma unroll
  for (int mf = 0; mf < 4; ++mf)
#pragma unroll
    for (int df = 0; df < 2; ++df)
#pragma unroll
      for (int r = 0; r < 4; ++r) {
        size_t row = base + mf * 16 + lg * 4 + r;
        out[row * 384 + h * 32 + df * 16 + li] = f2bf(o[mf][df][r]);
      }
}

extern "C" void kernel_launch(void* const* d_in, const int* in_sizes, int n_in,
                              void* d_out, int out_size, void* d_ws, size_t ws_size,
                              hipStream_t stream) {
  const float* x      = (const float*)d_in[0];
  const float* qkv_w  = (const float*)d_in[1];
  const float* qkv_b  = (const float*)d_in[2];
  const float* proj_w = (const float*)d_in[3];
  const float* proj_b = (const float*)d_in[4];
  const float* rel    = (const float*)d_in[5];
  const float* g1     = (const float*)d_in[6];
  const float* b1     = (const float*)d_in[7];
  const float* g2     = (const float*)d_in[8];
  const float* b2     = (const float*)d_in[9];
  const float* fc1_w  = (const float*)d_in[10];
  const float* fc1_b  = (const float*)d_in[11];
  const float* fc2_w  = (const float*)d_in[12];
  const float* fc2_b  = (const float*)d_in[13];
  const float* mask   = (const float*)d_in[14];
  float* out = (float*)d_out;
  char* ws = (char*)d_ws;

  const int M = 131072;  // B * H * W tokens
  // workspace (lifetime-checked):
  //   hw     [0, 100663296)           written ln1, read qkv GEMM, then dead
  //   bmask  [0, 25165824)            written AFTER qkv (hw dead), read attn, then dead
  //   ln2o   [0, 100663296)           written projln (bmask dead), read fc1
  //   qkv    [100663296, 402653184)   dead after attn
  //   hmid   [100663296, 503316480)   written fc1 (qkv+attn_o dead)
  //   attn_o [402653184, 503316480)   dead after projln
  //   x1b    [503316480, 603979776)
  //   wts    [603979776, 607518720)
  //   xb     [607518720, 708182016)
  unsigned short* hw     = (unsigned short*)ws;
  unsigned short* bmask  = (unsigned short*)ws;
  unsigned short* ln2o   = (unsigned short*)ws;
  unsigned short* qkv    = (unsigned short*)(ws + 100663296);
  unsigned short* hmid   = (unsigned short*)(ws + 100663296);
  unsigned short* attn_o = (unsigned short*)(ws + 402653184);
  unsigned short* x1b    = (unsigned short*)(ws + 503316480);
  unsigned short* wq     = (unsigned short*)(ws + 603979776);
  unsigned short* wp     = wq + 442368;
  unsigned short* w1     = wp + 147456;
  unsigned short* w2     = w1 + 589824;
  unsigned short* xb     = (unsigned short*)(ws + 607518720);

  // fused weight casts (wq|wp|w1|w2 contiguous)
  cvt_all<<<(442368 + 147456 + 589824 + 589824 + 255) / 256, 256, 0, stream>>>(
      qkv_w, 442368, proj_w, 147456, fc1_w, 589824, fc2_w, 589824, wq);

  // LN1 + shift + window partition (also emits xb = bf16(x))
  ln_kernel<1><<<M / 4, 256, 0, stream>>>(x, g1, b1, hw, xb);

  // QKV projection (Q pre-scaled by 1/sqrt(32)): grid (M/256)*(1152/128)
  gemmT<4, 384, 9><<<512 * 9, 512, 0, stream>>>(hw, wq, qkv_b, M, 1152, qkv, nullptr, nullptr);

  // bmask precompute (hw now dead): 256*12*4096 / 256
  bmask_build<<<49152, 256, 0, stream>>>(rel, mask, bmask);

  // windowed attention (one head-triple per block.y)
  attn_kernel<<<dim3(2048, 3), 256, 0, stream>>>(qkv, bmask, attn_o);

  // proj + window reverse + unshift + residual + LN2 (fused): M/128 blocks
  projln<<<1024, 512, 0, stream>>>(attn_o, wp, proj_b, xb, g2, b2, x1b, ln2o);

  // FC1 + GELU
  gemmT<1, 384, 12><<<512 * 12, 512, 0, stream>>>(ln2o, w1, fc1_b, M, 1536, hmid, nullptr, nullptr);

  // FC2 + residual(x1 bf16) -> out (f32)
  gemmT<3, 1536, 3><<<512 * 3, 512, 0, stream>>>(hmid, w2, fc2_b, M, 384, nullptr, x1b, out);
}

// Round 19
// 1104.062 us; speedup vs baseline: 1.0258x; 1.0258x over previous
//
#include <hip/hip_runtime.h>
#include <hip/hip_bf16.h>
#include <math.h>

typedef __attribute__((ext_vector_type(4))) float f32x4;
typedef __attribute__((ext_vector_type(8))) short bf16x8;

__device__ __forceinline__ unsigned short f2bf(float f) {
  unsigned int x = __builtin_bit_cast(unsigned int, f);
  x += 0x7fffu + ((x >> 16) & 1u);
  return (unsigned short)(x >> 16);
}
__device__ __forceinline__ float bf2f(unsigned short u) {
  unsigned int x = ((unsigned int)u) << 16;
  return __builtin_bit_cast(float, x);
}

__device__ __forceinline__ void gload_lds16(const void* g, void* l) {
  __builtin_amdgcn_global_load_lds(
      (const __attribute__((address_space(1))) unsigned int*)g,
      (__attribute__((address_space(3))) unsigned int*)l, 16, 0, 0);
}

// ---------------- fused f32 -> bf16 weight casts ----------------
__global__ void cvt_all(const float* __restrict__ s0, int n0, const float* __restrict__ s1, int n1,
                        const float* __restrict__ s2, int n2, const float* __restrict__ s3, int n3,
                        unsigned short* __restrict__ d) {
  int i = blockIdx.x * 256 + threadIdx.x;
  if (i >= n0 + n1 + n2 + n3) return;
  const float* s;
  int off;
  if (i < n0) { s = s0; off = 0; }
  else if (i < n0 + n1) { s = s1; off = n0; }
  else if (i < n0 + n1 + n2) { s = s2; off = n0 + n1; }
  else { s = s3; off = n0 + n1 + n2; }
  d[i] = f2bf(s[i - off]);
}

// ---------------- LayerNorm, f32 input (REMAP: window gather + xb emit) ----------------
template <int REMAP>
__global__ __launch_bounds__(256)
void ln_kernel(const float* __restrict__ x, const float* __restrict__ g,
               const float* __restrict__ b, unsigned short* __restrict__ dst_o,
               unsigned short* __restrict__ xb) {
  int r = blockIdx.x * 4 + (threadIdx.x >> 6);
  int lane = threadIdx.x & 63;
  size_t src;
  if (REMAP) {
    int w = r >> 6, t = r & 63;
    int bb = w >> 8, wi = (w >> 4) & 15, wj = w & 15;
    int i = t >> 3, j = t & 7;
    int p = (wi * 8 + i + 4) & 127, q = (wj * 8 + j + 4) & 127;
    src = ((size_t)bb * 16384 + p * 128 + q) * 384;
  } else {
    src = (size_t)r * 384;
  }
  float v[6];
  float s = 0.f, s2 = 0.f;
#pragma unroll
  for (int m = 0; m < 6; ++m) {
    v[m] = x[src + lane + 64 * m];
    s += v[m];
    s2 += v[m] * v[m];
  }
  if (REMAP) {
#pragma unroll
    for (int m = 0; m < 6; ++m) xb[src + lane + 64 * m] = f2bf(v[m]);
  }
#pragma unroll
  for (int o2 = 1; o2 < 64; o2 <<= 1) {
    s += __shfl_xor(s, o2);
    s2 += __shfl_xor(s2, o2);
  }
  float mu = s * (1.f / 384.f);
  float var = s2 * (1.f / 384.f) - mu * mu;
  float ri = rsqrtf(var + 1e-5f);
  size_t dst = (size_t)r * 384;
#pragma unroll
  for (int m = 0; m < 6; ++m) {
    int c = lane + 64 * m;
    dst_o[dst + c] = f2bf((v[m] - mu) * ri * g[c] + b[c]);
  }
}

// ---------------- LayerNorm, bf16 input ----------------
__global__ __launch_bounds__(256)
void ln_bf16(const unsigned short* __restrict__ x, const float* __restrict__ g,
             const float* __restrict__ b, unsigned short* __restrict__ dst_o) {
  int r = blockIdx.x * 4 + (threadIdx.x >> 6);
  int lane = threadIdx.x & 63;
  size_t src = (size_t)r * 384;
  float v[6];
  float s = 0.f, s2 = 0.f;
#pragma unroll
  for (int m = 0; m < 3; ++m) {
    unsigned int u = *(const unsigned int*)&x[src + lane * 2 + 128 * m];
    v[2 * m] = bf2f((unsigned short)(u & 0xffffu));
    v[2 * m + 1] = bf2f((unsigned short)(u >> 16));
    s += v[2 * m] + v[2 * m + 1];
    s2 += v[2 * m] * v[2 * m] + v[2 * m + 1] * v[2 * m + 1];
  }
#pragma unroll
  for (int o2 = 1; o2 < 64; o2 <<= 1) {
    s += __shfl_xor(s, o2);
    s2 += __shfl_xor(s2, o2);
  }
  float mu = s * (1.f / 384.f);
  float var = s2 * (1.f / 384.f) - mu * mu;
  float ri = rsqrtf(var + 1e-5f);
#pragma unroll
  for (int m = 0; m < 3; ++m) {
    int c = lane * 2 + 128 * m;
    unsigned int lo = f2bf((v[2 * m] - mu) * ri * g[c] + b[c]);
    unsigned int hi = f2bf((v[2 * m + 1] - mu) * ri * g[c + 1] + b[c + 1]);
    *(unsigned int*)&dst_o[src + c] = lo | (hi << 16);
  }
}

// ---------------- GEMM: C(M,N) = A(M,K) * B(N,K)^T ----------------
// Best-measured configuration (R15, 1102us total). Depth-2 pipeline:
// tri-buffer (3x24KB), counted vmcnt(3) per tile (stage(t) done, stage(t+1)
// in flight — T4, never 0 mid-loop), stage(t+2) issued post-barrier.
// Race-free fencing (R7 construction, replay-stable): own-vmcnt BEFORE
// s_barrier + sched_barrier(0) after (rule #18 — raw s_barrier is not a
// compiler fence). Buffer indices/k-offsets compile-time (nk%3==0, full
// unroll). BM=256, BN=128, BK=32, 512 thr / 8 waves, wave 64x64, acc[4][4].
// Swizzle (64B rows): LDS[row][g] = G[row][g ^ ((row>>1)&3)], both sides.
// EPI 0: bf16(acc+bias) | 1: bf16(gelu) | 2: proj scatter+bf16resid->bf16 | 3: f32+resid
template <int EPI, int K, int NT>
__global__ __launch_bounds__(512, 4)
void gemmT(const unsigned short* __restrict__ A, const unsigned short* __restrict__ Bw,
           const float* __restrict__ bias, int M, int N,
           unsigned short* __restrict__ Obf, const unsigned short* __restrict__ resid,
           float* __restrict__ Of) {
  __shared__ unsigned short lds[3 * 12288];  // 3 bufs x (A 256x32 + B 128x32) = 72 KB
  const int tid = threadIdx.x;
  const int lane = tid & 63;
  const int wid = tid >> 6;               // 0..7
  const int wm = wid >> 1, wn = wid & 1;  // wave grid 4M x 2N, wave tile 64x64
  const int li = lane & 15, lg = lane >> 4;

  // bijective XCD swizzle (m204)
  const int nwg = gridDim.x;
  const int orig = blockIdx.x;
  const int q = nwg >> 3, r = nwg & 7;
  const int xcd = orig & 7, loc = orig >> 3;
  const int wg = (xcd < r ? xcd * (q + 1) : r * (q + 1) + (xcd - r) * q) + loc;
  const int m0 = (wg / NT) * 256;
  const int n0 = (wg % NT) * 128;

  // staging: row = tid>>2 (0..127/round), grain = tid&3 (16B each);
  // pre-swizzled source grain = grain ^ ((row>>1)&3). A: 2 rounds; B: 1.
  const int srow = tid >> 2;
  const int scol = ((tid & 3) ^ ((srow >> 1) & 3)) * 8;
  const unsigned short* gA0 = A + (size_t)(m0 + srow) * K + scol;
  const unsigned short* gA1 = A + (size_t)(m0 + 128 + srow) * K + scol;
  const unsigned short* gB0 = Bw + (size_t)(n0 + srow) * K + scol;

  constexpr int nk = K >> 5;                   // 12 or 48 (div by 3)
  const int gsw = (lg ^ ((li >> 1) & 3)) * 8;  // frag-read swizzled grain
  f32x4 acc[4][4] = {};

  // prologue: 2 stages in flight (tiles 0,1), no drain
  gload_lds16(gA0, lds + wid * 512);
  gload_lds16(gA1, lds + 4096 + wid * 512);
  gload_lds16(gB0, lds + 8192 + wid * 512);
  gload_lds16(gA0 + 32, lds + 12288 + wid * 512);
  gload_lds16(gA1 + 32, lds + 12288 + 4096 + wid * 512);
  gload_lds16(gB0 + 32, lds + 12288 + 8192 + wid * 512);

#pragma unroll
  for (int t = 0; t < nk; ++t) {  // full unroll: bufs & k-offsets constexpr
    // own stage(t) done; stage(t+1) stays in flight (counted, T4)
    if (t < nk - 1) {
      asm volatile("s_waitcnt vmcnt(3)" ::: "memory");
    } else {
      asm volatile("s_waitcnt vmcnt(0)" ::: "memory");
    }
    __builtin_amdgcn_s_barrier();        // all waves' stage(t) complete
    __builtin_amdgcn_sched_barrier(0);   // fence: nothing moves above (rule #18)
    unsigned short* const cur = lds + (t % 3) * 12288;
    if (t + 2 < nk) {  // stage 2 tiles ahead into buf (t+2)%3 (free: last read at t-1)
      unsigned short* const nxt = lds + ((t + 2) % 3) * 12288;
      gload_lds16(gA0 + (t + 2) * 32, nxt + wid * 512);
      gload_lds16(gA1 + (t + 2) * 32, nxt + 4096 + wid * 512);
      gload_lds16(gB0 + (t + 2) * 32, nxt + 8192 + wid * 512);
    }
    bf16x8 a[4], b[4];
#pragma unroll
    for (int f = 0; f < 4; ++f) {
      a[f] = *(const bf16x8*)&cur[(wm * 64 + f * 16 + li) * 32 + gsw];
      b[f] = *(const bf16x8*)&cur[8192 + (wn * 64 + f * 16 + li) * 32 + gsw];
    }
    __builtin_amdgcn_s_setprio(1);
#pragma unroll
    for (int mf = 0; mf < 4; ++mf)
#pragma unroll
      for (int nf = 0; nf < 4; ++nf)
        acc[mf][nf] = __builtin_amdgcn_mfma_f32_16x16x32_bf16(a[mf], b[nf], acc[mf][nf], 0, 0, 0);
    __builtin_amdgcn_s_setprio(0);
    // no trailing barrier: next tile's vmcnt+barrier is the sync point
  }

  // epilogue: C/D layout col = lane&15, row = (lane>>4)*4 + reg
#pragma unroll
  for (int mf = 0; mf < 4; ++mf) {
#pragma unroll
    for (int r2 = 0; r2 < 4; ++r2) {
      int mrow = m0 + wm * 64 + mf * 16 + lg * 4 + r2;
      size_t orow = (size_t)mrow;
      if (EPI == 2) {
        int w = mrow >> 6, t = mrow & 63;
        int bb2 = w >> 8, wi = (w >> 4) & 15, wj = w & 15;
        int i = t >> 3, j = t & 7;
        int p = (wi * 8 + i + 4) & 127, qq = (wj * 8 + j + 4) & 127;
        orow = (size_t)bb2 * 16384 + p * 128 + qq;
      }
#pragma unroll
      for (int nf = 0; nf < 4; ++nf) {
        int col = n0 + wn * 64 + nf * 16 + li;
        float v = acc[mf][nf][r2] + bias[col];
        if (EPI == 0) {
          Obf[(size_t)mrow * N + col] = f2bf(v);
        } else if (EPI == 1) {
          float y = 1.5957691f * (v + 0.044715f * v * v * v);
          float gl = v * __builtin_amdgcn_rcpf(1.f + __expf(-y));
          Obf[(size_t)mrow * N + col] = f2bf(gl);
        } else if (EPI == 2) {
          Obf[orow * 384 + col] = f2bf(v + bf2f(resid[orow * 384 + col]));
        } else {
          Of[(size_t)mrow * N + col] = v + bf2f(resid[(size_t)mrow * N + col]);
        }
      }
    }
  }
}

// ---------------- windowed attention: block = (window, head-triple); 4 waves ----------------
__global__ __launch_bounds__(256, 2)
void attn_kernel(const unsigned short* __restrict__ qkv, const float* __restrict__ btab,
                 const float* __restrict__ mask, unsigned short* __restrict__ out) {
  __shared__ unsigned short v_lds[4][64 * 40];  // V tile, row stride 40
  __shared__ unsigned short p_lds[4][64 * 72];  // P tile, row stride 72
  const int w = blockIdx.x;
  const int hi = blockIdx.y;  // 0..2
  const int tid = threadIdx.x;
  const int wid = tid >> 6, lane = tid & 63;
  const int li = lane & 15, lg = lane >> 4;
  const float* mrow = mask + (size_t)(w & 255) * 4096;
  const size_t base = (size_t)w * 64;
  const float SC = 0.17677669529663688f;  // 32^-0.5

  int h = wid * 3 + hi;
  bf16x8 aq[4], bk[4];
#pragma unroll
  for (int f = 0; f < 4; ++f) {
    size_t off = (base + f * 16 + li) * 1152 + h * 32 + lg * 8;
    aq[f] = *(const bf16x8*)&qkv[off];
    bk[f] = *(const bf16x8*)&qkv[off + 384];
  }
  f32x4 s[4][4] = {};
#pragma unroll
  for (int mf = 0; mf < 4; ++mf)
#pragma unroll
    for (int nf = 0; nf < 4; ++nf)
      s[mf][nf] = __builtin_amdgcn_mfma_f32_16x16x32_bf16(aq[mf], bk[nf], s[mf][nf], 0, 0, 0);

  {
    const unsigned short* vp = &qkv[(base + lane) * 1152 + 768 + h * 32];
    unsigned short* dp = &v_lds[wid][lane * 40];
#pragma unroll
    for (int c = 0; c < 4; ++c) *(bf16x8*)&dp[c * 8] = *(const bf16x8*)&vp[c * 8];
  }

#pragma unroll
  for (int mf = 0; mf < 4; ++mf) {
#pragma unroll
    for (int r = 0; r < 4; ++r) {
      int m = mf * 16 + lg * 4 + r;
      float mx = -1e30f;
#pragma unroll
      for (int nf = 0; nf < 4; ++nf) {
        int n = nf * 16 + li;
        int ridx = ((m >> 3) - (n >> 3) + 7) * 15 + (m & 7) - (n & 7) + 7;
        float val = s[mf][nf][r] * SC + btab[ridx * 12 + h] + mrow[m * 64 + n];
        s[mf][nf][r] = val;
        mx = fmaxf(mx, val);
      }
#pragma unroll
      for (int o2 = 1; o2 < 16; o2 <<= 1) mx = fmaxf(mx, __shfl_xor(mx, o2));
      float sum = 0.f;
#pragma unroll
      for (int nf = 0; nf < 4; ++nf) {
        float e = __expf(s[mf][nf][r] - mx);
        s[mf][nf][r] = e;
        sum += e;
      }
#pragma unroll
      for (int o2 = 1; o2 < 16; o2 <<= 1) sum += __shfl_xor(sum, o2);
      float inv = __builtin_amdgcn_rcpf(sum);
#pragma unroll
      for (int nf = 0; nf < 4; ++nf) s[mf][nf][r] *= inv;
    }
  }

#pragma unroll
  for (int mf = 0; mf < 4; ++mf)
#pragma unroll
    for (int nf = 0; nf < 4; ++nf)
#pragma unroll
      for (int r = 0; r < 4; ++r) {
        int m = mf * 16 + lg * 4 + r, n = nf * 16 + li;
        p_lds[wid][m * 72 + n] = f2bf(s[mf][nf][r]);
      }

  f32x4 o[4][2] = {};
#pragma unroll
  for (int kf = 0; kf < 2; ++kf) {
    bf16x8 bv[2];
#pragma unroll
    for (int df = 0; df < 2; ++df) {
      bf16x8 t;
#pragma unroll
      for (int e = 0; e < 8; ++e)
        t[e] = (short)v_lds[wid][(kf * 32 + lg * 8 + e) * 40 + df * 16 + li];
      bv[df] = t;
    }
#pragma unroll
    for (int mf = 0; mf < 4; ++mf) {
      bf16x8 pa = *(const bf16x8*)&p_lds[wid][(mf * 16 + li) * 72 + kf * 32 + lg * 8];
#pragma unroll
      for (int df = 0; df < 2; ++df)
        o[mf][df] = __builtin_amdgcn_mfma_f32_16x16x32_bf16(pa, bv[df], o[mf][df], 0, 0, 0);
    }
  }

#pragma unroll
  for (int mf = 0; mf < 4; ++mf)
#pragma unroll
    for (int df = 0; df < 2; ++df)
#pragma unroll
      for (int r = 0; r < 4; ++r) {
        size_t row = base + mf * 16 + lg * 4 + r;
        out[row * 384 + h * 32 + df * 16 + li] = f2bf(o[mf][df][r]);
      }
}

extern "C" void kernel_launch(void* const* d_in, const int* in_sizes, int n_in,
                              void* d_out, int out_size, void* d_ws, size_t ws_size,
                              hipStream_t stream) {
  const float* x      = (const float*)d_in[0];
  const float* qkv_w  = (const float*)d_in[1];
  const float* qkv_b  = (const float*)d_in[2];
  const float* proj_w = (const float*)d_in[3];
  const float* proj_b = (const float*)d_in[4];
  const float* rel    = (const float*)d_in[5];
  const float* g1     = (const float*)d_in[6];
  const float* b1     = (const float*)d_in[7];
  const float* g2     = (const float*)d_in[8];
  const float* b2     = (const float*)d_in[9];
  const float* fc1_w  = (const float*)d_in[10];
  const float* fc1_b  = (const float*)d_in[11];
  const float* fc2_w  = (const float*)d_in[12];
  const float* fc2_b  = (const float*)d_in[13];
  const float* mask   = (const float*)d_in[14];
  float* out = (float*)d_out;
  char* ws = (char*)d_ws;

  const int M = 131072;  // B * H * W tokens
  unsigned short* hw     = (unsigned short*)ws;
  unsigned short* qkv    = (unsigned short*)(ws + 100663296);
  unsigned short* hmid   = (unsigned short*)ws;
  unsigned short* attn_o = (unsigned short*)(ws + 402653184);
  unsigned short* ln2o   = attn_o;
  unsigned short* x1b    = (unsigned short*)(ws + 503316480);
  unsigned short* wq     = (unsigned short*)(ws + 603979776);
  unsigned short* wp     = wq + 442368;
  unsigned short* w1     = wp + 147456;
  unsigned short* w2     = w1 + 589824;
  unsigned short* xb     = (unsigned short*)(ws + 607518720);

  // fused weight casts (wq|wp|w1|w2 contiguous)
  cvt_all<<<(442368 + 147456 + 589824 + 589824 + 255) / 256, 256, 0, stream>>>(
      qkv_w, 442368, proj_w, 147456, fc1_w, 589824, fc2_w, 589824, wq);

  // LN1 + shift + window partition (also emits xb = bf16(x))
  ln_kernel<1><<<M / 4, 256, 0, stream>>>(x, g1, b1, hw, xb);

  // QKV projection: grid (M/256)*(1152/128) = 512*9
  gemmT<0, 384, 9><<<512 * 9, 512, 0, stream>>>(hw, wq, qkv_b, M, 1152, qkv, nullptr, nullptr);

  // windowed attention (one head-triple per block.y)
  attn_kernel<<<dim3(2048, 3), 256, 0, stream>>>(qkv, rel, mask, attn_o);

  // proj + window reverse + unshift + residual(xb bf16) -> x1 (bf16): 512*3
  gemmT<2, 384, 3><<<512 * 3, 512, 0, stream>>>(attn_o, wp, proj_b, M, 384, x1b, xb, nullptr);

  // LN2 (bf16 in)
  ln_bf16<<<M / 4, 256, 0, stream>>>(x1b, g2, b2, ln2o);

  // FC1 + GELU: 512*12
  gemmT<1, 384, 12><<<512 * 12, 512, 0, stream>>>(ln2o, w1, fc1_b, M, 1536, hmid, nullptr, nullptr);

  // FC2 + residual(x1 bf16) -> out (f32): 512*3
  gemmT<3, 1536, 3><<<512 * 3, 512, 0, stream>>>(hmid, w2, fc2_b, M, 384, nullptr, x1b, out);
}

// Round 20
// 1097.127 us; speedup vs baseline: 1.0323x; 1.0063x over previous
//
#include <hip/hip_runtime.h>
#include <hip/hip_bf16.h>
#include <math.h>

typedef __attribute__((ext_vector_type(4))) float f32x4;
typedef __attribute__((ext_vector_type(8))) short bf16x8;

__device__ __forceinline__ unsigned short f2bf(float f) {
  unsigned int x = __builtin_bit_cast(unsigned int, f);
  x += 0x7fffu + ((x >> 16) & 1u);
  return (unsigned short)(x >> 16);
}
__device__ __forceinline__ float bf2f(unsigned short u) {
  unsigned int x = ((unsigned int)u) << 16;
  return __builtin_bit_cast(float, x);
}

__device__ __forceinline__ void gload_lds16(const void* g, void* l) {
  __builtin_amdgcn_global_load_lds(
      (const __attribute__((address_space(1))) unsigned int*)g,
      (__attribute__((address_space(3))) unsigned int*)l, 16, 0, 0);
}

// ---------------- fused f32 -> bf16 weight casts ----------------
__global__ void cvt_all(const float* __restrict__ s0, int n0, const float* __restrict__ s1, int n1,
                        const float* __restrict__ s2, int n2, const float* __restrict__ s3, int n3,
                        unsigned short* __restrict__ d) {
  int i = blockIdx.x * 256 + threadIdx.x;
  if (i >= n0 + n1 + n2 + n3) return;
  const float* s;
  int off;
  if (i < n0) { s = s0; off = 0; }
  else if (i < n0 + n1) { s = s1; off = n0; }
  else if (i < n0 + n1 + n2) { s = s2; off = n0 + n1; }
  else { s = s3; off = n0 + n1 + n2; }
  d[i] = f2bf(s[i - off]);
}

// ---------------- LayerNorm, f32 input (REMAP: window gather + xb emit) ----------------
template <int REMAP>
__global__ __launch_bounds__(256)
void ln_kernel(const float* __restrict__ x, const float* __restrict__ g,
               const float* __restrict__ b, unsigned short* __restrict__ dst_o,
               unsigned short* __restrict__ xb) {
  int r = blockIdx.x * 4 + (threadIdx.x >> 6);
  int lane = threadIdx.x & 63;
  size_t src;
  if (REMAP) {
    int w = r >> 6, t = r & 63;
    int bb = w >> 8, wi = (w >> 4) & 15, wj = w & 15;
    int i = t >> 3, j = t & 7;
    int p = (wi * 8 + i + 4) & 127, q = (wj * 8 + j + 4) & 127;
    src = ((size_t)bb * 16384 + p * 128 + q) * 384;
  } else {
    src = (size_t)r * 384;
  }
  float v[6];
  float s = 0.f, s2 = 0.f;
#pragma unroll
  for (int m = 0; m < 6; ++m) {
    v[m] = x[src + lane + 64 * m];
    s += v[m];
    s2 += v[m] * v[m];
  }
  if (REMAP) {
#pragma unroll
    for (int m = 0; m < 6; ++m) xb[src + lane + 64 * m] = f2bf(v[m]);
  }
#pragma unroll
  for (int o2 = 1; o2 < 64; o2 <<= 1) {
    s += __shfl_xor(s, o2);
    s2 += __shfl_xor(s2, o2);
  }
  float mu = s * (1.f / 384.f);
  float var = s2 * (1.f / 384.f) - mu * mu;
  float ri = rsqrtf(var + 1e-5f);
  size_t dst = (size_t)r * 384;
#pragma unroll
  for (int m = 0; m < 6; ++m) {
    int c = lane + 64 * m;
    dst_o[dst + c] = f2bf((v[m] - mu) * ri * g[c] + b[c]);
  }
}

// ---------------- LayerNorm, bf16 input ----------------
__global__ __launch_bounds__(256)
void ln_bf16(const unsigned short* __restrict__ x, const float* __restrict__ g,
             const float* __restrict__ b, unsigned short* __restrict__ dst_o) {
  int r = blockIdx.x * 4 + (threadIdx.x >> 6);
  int lane = threadIdx.x & 63;
  size_t src = (size_t)r * 384;
  float v[6];
  float s = 0.f, s2 = 0.f;
#pragma unroll
  for (int m = 0; m < 3; ++m) {
    unsigned int u = *(const unsigned int*)&x[src + lane * 2 + 128 * m];
    v[2 * m] = bf2f((unsigned short)(u & 0xffffu));
    v[2 * m + 1] = bf2f((unsigned short)(u >> 16));
    s += v[2 * m] + v[2 * m + 1];
    s2 += v[2 * m] * v[2 * m] + v[2 * m + 1] * v[2 * m + 1];
  }
#pragma unroll
  for (int o2 = 1; o2 < 64; o2 <<= 1) {
    s += __shfl_xor(s, o2);
    s2 += __shfl_xor(s2, o2);
  }
  float mu = s * (1.f / 384.f);
  float var = s2 * (1.f / 384.f) - mu * mu;
  float ri = rsqrtf(var + 1e-5f);
#pragma unroll
  for (int m = 0; m < 3; ++m) {
    int c = lane * 2 + 128 * m;
    unsigned int lo = f2bf((v[2 * m] - mu) * ri * g[c] + b[c]);
    unsigned int hi = f2bf((v[2 * m + 1] - mu) * ri * g[c + 1] + b[c + 1]);
    *(unsigned int*)&dst_o[src + c] = lo | (hi << 16);
  }
}

// ---------------- GEMM: C(M,N) = A(M,K) * B(N,K)^T (R15/R19, best-measured) ----------------
// Depth-2 pipeline: tri-buffer (3x24KB), counted vmcnt(3) per tile, stage(t+2)
// post-barrier. R7-style fencing: own-vmcnt BEFORE s_barrier + sched_barrier(0)
// after (rule #18). Full unroll -> constexpr bufs/offsets. BM=256, BN=128,
// BK=32, 512 thr / 8 waves, wave 64x64, acc[4][4]. Both-sides swizzle.
// EPI 0: bf16(acc+bias) | 1: bf16(gelu) | 2: proj scatter+bf16resid->bf16 | 3: f32+resid
template <int EPI, int K, int NT>
__global__ __launch_bounds__(512, 4)
void gemmT(const unsigned short* __restrict__ A, const unsigned short* __restrict__ Bw,
           const float* __restrict__ bias, int M, int N,
           unsigned short* __restrict__ Obf, const unsigned short* __restrict__ resid,
           float* __restrict__ Of) {
  __shared__ unsigned short lds[3 * 12288];
  const int tid = threadIdx.x;
  const int lane = tid & 63;
  const int wid = tid >> 6;
  const int wm = wid >> 1, wn = wid & 1;
  const int li = lane & 15, lg = lane >> 4;

  const int nwg = gridDim.x;
  const int orig = blockIdx.x;
  const int q = nwg >> 3, r = nwg & 7;
  const int xcd = orig & 7, loc = orig >> 3;
  const int wg = (xcd < r ? xcd * (q + 1) : r * (q + 1) + (xcd - r) * q) + loc;
  const int m0 = (wg / NT) * 256;
  const int n0 = (wg % NT) * 128;

  const int srow = tid >> 2;
  const int scol = ((tid & 3) ^ ((srow >> 1) & 3)) * 8;
  const unsigned short* gA0 = A + (size_t)(m0 + srow) * K + scol;
  const unsigned short* gA1 = A + (size_t)(m0 + 128 + srow) * K + scol;
  const unsigned short* gB0 = Bw + (size_t)(n0 + srow) * K + scol;

  constexpr int nk = K >> 5;
  const int gsw = (lg ^ ((li >> 1) & 3)) * 8;
  f32x4 acc[4][4] = {};

  gload_lds16(gA0, lds + wid * 512);
  gload_lds16(gA1, lds + 4096 + wid * 512);
  gload_lds16(gB0, lds + 8192 + wid * 512);
  gload_lds16(gA0 + 32, lds + 12288 + wid * 512);
  gload_lds16(gA1 + 32, lds + 12288 + 4096 + wid * 512);
  gload_lds16(gB0 + 32, lds + 12288 + 8192 + wid * 512);

#pragma unroll
  for (int t = 0; t < nk; ++t) {
    if (t < nk - 1) {
      asm volatile("s_waitcnt vmcnt(3)" ::: "memory");
    } else {
      asm volatile("s_waitcnt vmcnt(0)" ::: "memory");
    }
    __builtin_amdgcn_s_barrier();
    __builtin_amdgcn_sched_barrier(0);
    unsigned short* const cur = lds + (t % 3) * 12288;
    if (t + 2 < nk) {
      unsigned short* const nxt = lds + ((t + 2) % 3) * 12288;
      gload_lds16(gA0 + (t + 2) * 32, nxt + wid * 512);
      gload_lds16(gA1 + (t + 2) * 32, nxt + 4096 + wid * 512);
      gload_lds16(gB0 + (t + 2) * 32, nxt + 8192 + wid * 512);
    }
    bf16x8 a[4], b[4];
#pragma unroll
    for (int f = 0; f < 4; ++f) {
      a[f] = *(const bf16x8*)&cur[(wm * 64 + f * 16 + li) * 32 + gsw];
      b[f] = *(const bf16x8*)&cur[8192 + (wn * 64 + f * 16 + li) * 32 + gsw];
    }
    __builtin_amdgcn_s_setprio(1);
#pragma unroll
    for (int mf = 0; mf < 4; ++mf)
#pragma unroll
      for (int nf = 0; nf < 4; ++nf)
        acc[mf][nf] = __builtin_amdgcn_mfma_f32_16x16x32_bf16(a[mf], b[nf], acc[mf][nf], 0, 0, 0);
    __builtin_amdgcn_s_setprio(0);
  }

#pragma unroll
  for (int mf = 0; mf < 4; ++mf) {
#pragma unroll
    for (int r2 = 0; r2 < 4; ++r2) {
      int mrow = m0 + wm * 64 + mf * 16 + lg * 4 + r2;
      size_t orow = (size_t)mrow;
      if (EPI == 2) {
        int w = mrow >> 6, t = mrow & 63;
        int bb2 = w >> 8, wi = (w >> 4) & 15, wj = w & 15;
        int i = t >> 3, j = t & 7;
        int p = (wi * 8 + i + 4) & 127, qq = (wj * 8 + j + 4) & 127;
        orow = (size_t)bb2 * 16384 + p * 128 + qq;
      }
#pragma unroll
      for (int nf = 0; nf < 4; ++nf) {
        int col = n0 + wn * 64 + nf * 16 + li;
        float v = acc[mf][nf][r2] + bias[col];
        if (EPI == 0) {
          Obf[(size_t)mrow * N + col] = f2bf(v);
        } else if (EPI == 1) {
          float y = 1.5957691f * (v + 0.044715f * v * v * v);
          float gl = v * __builtin_amdgcn_rcpf(1.f + __expf(-y));
          Obf[(size_t)mrow * N + col] = f2bf(gl);
        } else if (EPI == 2) {
          Obf[orow * 384 + col] = f2bf(v + bf2f(resid[orow * 384 + col]));
        } else {
          Of[(size_t)mrow * N + col] = v + bf2f(resid[(size_t)mrow * N + col]);
        }
      }
    }
  }
}

// ---------------- windowed attention: block = (window, head-triple); 4 waves ----------------
// R20: LDS diet (v stride 40->36, p stride 72->66: 56KB -> 51KB) +
// launch_bounds(256,3) -> 3 blocks/CU (2->3 waves/SIMD) for the latency-bound
// scattered Q/K/V gathers. Bank check: p-stride 66 = 132B lane stride = +1
// bank per lane (conflict-free both sides); v-stride 36 <= 2-way (free, m136).
// No barriers in this kernel (all LDS slices wave-private) -> stride change
// is race-free by construction.
__global__ __launch_bounds__(256, 3)
void attn_kernel(const unsigned short* __restrict__ qkv, const float* __restrict__ btab,
                 const float* __restrict__ mask, unsigned short* __restrict__ out) {
  __shared__ unsigned short v_lds[4][64 * 36];  // V tile, row stride 36
  __shared__ unsigned short p_lds[4][64 * 66];  // P tile, row stride 66
  const int w = blockIdx.x;
  const int hi = blockIdx.y;  // 0..2
  const int tid = threadIdx.x;
  const int wid = tid >> 6, lane = tid & 63;
  const int li = lane & 15, lg = lane >> 4;
  const float* mrow = mask + (size_t)(w & 255) * 4096;
  const size_t base = (size_t)w * 64;
  const float SC = 0.17677669529663688f;  // 32^-0.5

  int h = wid * 3 + hi;
  bf16x8 aq[4], bk[4];
#pragma unroll
  for (int f = 0; f < 4; ++f) {
    size_t off = (base + f * 16 + li) * 1152 + h * 32 + lg * 8;
    aq[f] = *(const bf16x8*)&qkv[off];
    bk[f] = *(const bf16x8*)&qkv[off + 384];
  }
  f32x4 s[4][4] = {};
#pragma unroll
  for (int mf = 0; mf < 4; ++mf)
#pragma unroll
    for (int nf = 0; nf < 4; ++nf)
      s[mf][nf] = __builtin_amdgcn_mfma_f32_16x16x32_bf16(aq[mf], bk[nf], s[mf][nf], 0, 0, 0);

  {
    const unsigned short* vp = &qkv[(base + lane) * 1152 + 768 + h * 32];
    unsigned short* dp = &v_lds[wid][lane * 36];
#pragma unroll
    for (int c = 0; c < 4; ++c) *(bf16x8*)&dp[c * 8] = *(const bf16x8*)&vp[c * 8];
  }

#pragma unroll
  for (int mf = 0; mf < 4; ++mf) {
#pragma unroll
    for (int r = 0; r < 4; ++r) {
      int m = mf * 16 + lg * 4 + r;
      float mx = -1e30f;
#pragma unroll
      for (int nf = 0; nf < 4; ++nf) {
        int n = nf * 16 + li;
        int ridx = ((m >> 3) - (n >> 3) + 7) * 15 + (m & 7) - (n & 7) + 7;
        float val = s[mf][nf][r] * SC + btab[ridx * 12 + h] + mrow[m * 64 + n];
        s[mf][nf][r] = val;
        mx = fmaxf(mx, val);
      }
#pragma unroll
      for (int o2 = 1; o2 < 16; o2 <<= 1) mx = fmaxf(mx, __shfl_xor(mx, o2));
      float sum = 0.f;
#pragma unroll
      for (int nf = 0; nf < 4; ++nf) {
        float e = __expf(s[mf][nf][r] - mx);
        s[mf][nf][r] = e;
        sum += e;
      }
#pragma unroll
      for (int o2 = 1; o2 < 16; o2 <<= 1) sum += __shfl_xor(sum, o2);
      float inv = __builtin_amdgcn_rcpf(sum);
#pragma unroll
      for (int nf = 0; nf < 4; ++nf) s[mf][nf][r] *= inv;
    }
  }

#pragma unroll
  for (int mf = 0; mf < 4; ++mf)
#pragma unroll
    for (int nf = 0; nf < 4; ++nf)
#pragma unroll
      for (int r = 0; r < 4; ++r) {
        int m = mf * 16 + lg * 4 + r, n = nf * 16 + li;
        p_lds[wid][m * 66 + n] = f2bf(s[mf][nf][r]);
      }

  f32x4 o[4][2] = {};
#pragma unroll
  for (int kf = 0; kf < 2; ++kf) {
    bf16x8 bv[2];
#pragma unroll
    for (int df = 0; df < 2; ++df) {
      bf16x8 t;
#pragma unroll
      for (int e = 0; e < 8; ++e)
        t[e] = (short)v_lds[wid][(kf * 32 + lg * 8 + e) * 36 + df * 16 + li];
      bv[df] = t;
    }
#pragma unroll
    for (int mf = 0; mf < 4; ++mf) {
      bf16x8 pa = *(const bf16x8*)&p_lds[wid][(mf * 16 + li) * 66 + kf * 32 + lg * 8];
#pragma unroll
      for (int df = 0; df < 2; ++df)
        o[mf][df] = __builtin_amdgcn_mfma_f32_16x16x32_bf16(pa, bv[df], o[mf][df], 0, 0, 0);
    }
  }

#pragma unroll
  for (int mf = 0; mf < 4; ++mf)
#pragma unroll
    for (int df = 0; df < 2; ++df)
#pragma unroll
      for (int r = 0; r < 4; ++r) {
        size_t row = base + mf * 16 + lg * 4 + r;
        out[row * 384 + h * 32 + df * 16 + li] = f2bf(o[mf][df][r]);
      }
}

extern "C" void kernel_launch(void* const* d_in, const int* in_sizes, int n_in,
                              void* d_out, int out_size, void* d_ws, size_t ws_size,
                              hipStream_t stream) {
  const float* x      = (const float*)d_in[0];
  const float* qkv_w  = (const float*)d_in[1];
  const float* qkv_b  = (const float*)d_in[2];
  const float* proj_w = (const float*)d_in[3];
  const float* proj_b = (const float*)d_in[4];
  const float* rel    = (const float*)d_in[5];
  const float* g1     = (const float*)d_in[6];
  const float* b1     = (const float*)d_in[7];
  const float* g2     = (const float*)d_in[8];
  const float* b2     = (const float*)d_in[9];
  const float* fc1_w  = (const float*)d_in[10];
  const float* fc1_b  = (const float*)d_in[11];
  const float* fc2_w  = (const float*)d_in[12];
  const float* fc2_b  = (const float*)d_in[13];
  const float* mask   = (const float*)d_in[14];
  float* out = (float*)d_out;
  char* ws = (char*)d_ws;

  const int M = 131072;  // B * H * W tokens
  unsigned short* hw     = (unsigned short*)ws;
  unsigned short* qkv    = (unsigned short*)(ws + 100663296);
  unsigned short* hmid   = (unsigned short*)ws;
  unsigned short* attn_o = (unsigned short*)(ws + 402653184);
  unsigned short* ln2o   = attn_o;
  unsigned short* x1b    = (unsigned short*)(ws + 503316480);
  unsigned short* wq     = (unsigned short*)(ws + 603979776);
  unsigned short* wp     = wq + 442368;
  unsigned short* w1     = wp + 147456;
  unsigned short* w2     = w1 + 589824;
  unsigned short* xb     = (unsigned short*)(ws + 607518720);

  // fused weight casts (wq|wp|w1|w2 contiguous)
  cvt_all<<<(442368 + 147456 + 589824 + 589824 + 255) / 256, 256, 0, stream>>>(
      qkv_w, 442368, proj_w, 147456, fc1_w, 589824, fc2_w, 589824, wq);

  // LN1 + shift + window partition (also emits xb = bf16(x))
  ln_kernel<1><<<M / 4, 256, 0, stream>>>(x, g1, b1, hw, xb);

  // QKV projection: grid (M/256)*(1152/128) = 512*9
  gemmT<0, 384, 9><<<512 * 9, 512, 0, stream>>>(hw, wq, qkv_b, M, 1152, qkv, nullptr, nullptr);

  // windowed attention (one head-triple per block.y)
  attn_kernel<<<dim3(2048, 3), 256, 0, stream>>>(qkv, rel, mask, attn_o);

  // proj + window reverse + unshift + residual(xb bf16) -> x1 (bf16): 512*3
  gemmT<2, 384, 3><<<512 * 3, 512, 0, stream>>>(attn_o, wp, proj_b, M, 384, x1b, xb, nullptr);

  // LN2 (bf16 in)
  ln_bf16<<<M / 4, 256, 0, stream>>>(x1b, g2, b2, ln2o);

  // FC1 + GELU: 512*12
  gemmT<1, 384, 12><<<512 * 12, 512, 0, stream>>>(ln2o, w1, fc1_b, M, 1536, hmid, nullptr, nullptr);

  // FC2 + residual(x1 bf16) -> out (f32): 512*3
  gemmT<3, 1536, 3><<<512 * 3, 512, 0, stream>>>(hmid, w2, fc2_b, M, 384, nullptr, x1b, out);
}